// Round 10
// baseline (631.436 us; speedup 1.0000x reference)
//
#include <hip/hip_runtime.h>
#include <hip/hip_bf16.h>
#include <stdint.h>

#define B_ 32
#define S_ 2048
#define H_ 1024
#define U_ 1024

typedef __attribute__((ext_vector_type(8))) short short8;
typedef __attribute__((ext_vector_type(4))) float f32x4;

#define AS1 __attribute__((address_space(1)))
#define AS3 __attribute__((address_space(3)))
#define FENCE __builtin_amdgcn_sched_barrier(0)

__device__ __forceinline__ unsigned short f2bf(float f) {
  unsigned int u = __float_as_uint(f);
  u += 0x7fffu + ((u >> 16) & 1u);   // RNE
  return (unsigned short)(u >> 16);
}

// ---------- prep 1: W1 [H][U] f32 -> W1T [U][H] bf16 ----------
__global__ void k_transpose_w1(const float* __restrict__ W1, unsigned short* __restrict__ W1T) {
  __shared__ float tile[64][65];
  const int tx = threadIdx.x, ty = threadIdx.y;
  const int u0 = blockIdx.x * 64, h0 = blockIdx.y * 64;
#pragma unroll
  for (int i = 0; i < 16; ++i) {
    int hl = ty + i * 4;
    tile[hl][tx] = W1[(size_t)(h0 + hl) * U_ + (u0 + tx)];
  }
  __syncthreads();
#pragma unroll
  for (int i = 0; i < 16; ++i) {
    int ul = ty + i * 4;
    W1T[(size_t)(u0 + ul) * H_ + (h0 + tx)] = f2bf(tile[tx][ul]);
  }
}

// ---------- prep 2a: qpart[hs][b][u] = sum_{h in strip hs} query[b][h]*W2[h][u] ----------
__global__ void k_b1q_part(const float* __restrict__ query, const float* __restrict__ W2,
                           float* __restrict__ qpart) {
  __shared__ float q_sh[32 * 128];
  const int u = blockIdx.x * 256 + threadIdx.x;
  const int hs = blockIdx.y;                       // 8 strips of 128
  for (int i = threadIdx.x; i < 4096; i += 256) {
    const int b = i >> 7, h = i & 127;
    q_sh[i] = query[b * H_ + hs * 128 + h];
  }
  __syncthreads();
  float acc[32];
#pragma unroll
  for (int b = 0; b < 32; ++b) acc[b] = 0.f;
  for (int h = 0; h < 128; ++h) {
    const float w = W2[(size_t)(hs * 128 + h) * U_ + u];
#pragma unroll
    for (int b = 0; b < 32; ++b) acc[b] += q_sh[b * 128 + h] * w;
  }
#pragma unroll
  for (int b = 0; b < 32; ++b) qpart[((size_t)hs * 32 + b) * U_ + u] = acc[b];
}

// ---------- prep 2b: b1q[b][u] = b1[u]+b2[u]+sum_hs qpart ----------
__global__ void k_b1q_comb(const float* __restrict__ qpart, const float* __restrict__ b1,
                           const float* __restrict__ b2, float* __restrict__ b1q) {
  const int u = blockIdx.x * 256 + threadIdx.x;
  const int b = blockIdx.y;
  float s = b1[u] + b2[u];
#pragma unroll
  for (int hs = 0; hs < 8; ++hs) s += qpart[((size_t)hs * 32 + b) * U_ + u];
  b1q[b * U_ + u] = s;
}

// ---------- fused GEMM+tanh+V: B direct global->reg (L2-resident), A-only LDS ----------
// Tile 128x256xBK32, 8 waves (2x4), wave 64x64. LDS = As 2x8KB only (16 KB).
// B (W1T, 2 MB, L2/L3-resident) is loaded global->reg 1 step ahead, double reg-set
// (bX/bY, compile-time alternated): per wave 4x dwordx4, 16 u-rows x 64B = full lines.
// This removes B's 32 KB/step LDS reads + 16 KB writes -> LDS ~80 KB/CU/step < MFMA
// 1240 cyc -> matrix-pipe-bound structure. A: f32->reg->cvt->ds_write, 2-step deep
// (X/Y reg-sets). Per-step vmcnt(6) retires exactly A(t+1) (queue: A(t+1)2 drained by
// compiler's pre-MFMA B(t) wait; newer = A(t+2)2+B(t+1)4). Never vmcnt(0) mid-loop.
// A swizzle (r2-verified, 0 conflicts): chunk lc of row r at phys lc ^ ((r>>1)&3).
#define BM 128
#define BN 256
#define BK 32
#define NSTEP 32   // H_/BK

__global__ __launch_bounds__(512, 4)
void k_fused_score(const float* __restrict__ values,
                   const unsigned short* __restrict__ W1T,
                   const float* __restrict__ b1q, const float* __restrict__ V,
                   float* __restrict__ score_part) {
  __shared__ __align__(16) unsigned char smem[16384];
  unsigned short* As = (unsigned short*)smem;             // [2][128*32]
  float* scorebuf = (float*)smem;                          // alias post-loop

  const int tid = threadIdx.x;
  const int g = blockIdx.x;                  // 2048 = 512 bm x 4 bn
  const int seq = (g & 7) * 256 + (g >> 3);  // bijective XCD swizzle (2048 = 8*256)
  const int bn = seq & 3;
  const int bm = seq >> 2;

  const int lane = tid & 63, wid = tid >> 6;
  const int wm = wid >> 2, wn = wid & 3;     // 2 x 4 waves
  const int u0 = bn * BN;

  // A staging (regs): thread -> (row, logical chunk of 8 f32->bf16)
  const int arow = tid >> 2;                 // 0..127
  const int alc  = tid & 3;                  // logical chunk
  const int aplc = alc ^ ((arow >> 1) & 3);  // phys chunk (swizzled)
  const float* aSrcF = values + (size_t)(bm * BM + arow) * H_ + alc * 8;
  const int awoff = arow * 32 + aplc * 8;    // shorts, + slot*4096

  // fragment read swizzle (A)
  const int l15 = lane & 15, l16 = lane >> 4;
  const int fsq = ((l16 ^ ((lane >> 1) & 3)) << 3);   // shorts
  const int pA = (wm * 64 + l15) * 32 + fsq;          // + mf*512

  // B direct-load base: u = u0 + wn*64 + nf*16 + l15, k-chunk = l16
  const unsigned short* bSrcR = W1T + (size_t)(u0 + wn * 64 + l15) * H_ + l16 * 8;

  f32x4 acc[4][4];
#pragma unroll
  for (int mf = 0; mf < 4; ++mf)
#pragma unroll
    for (int nf = 0; nf < 4; ++nf) acc[mf][nf] = (f32x4){0.f, 0.f, 0.f, 0.f};

  float4 aX0, aX1, aY0, aY1;                 // A reg-sets
  short8 bX[4], bY[4];                       // B reg-sets (static idx via unroll)

#define ISSUE_SET(P0, P1, tt) { \
    const float4* p_ = (const float4*)(aSrcF + (tt) * BK); \
    P0 = p_[0]; P1 = p_[1]; }

#define WRITE_SET(P0, P1, slot) { \
    short8 w_; \
    w_[0]=f2bf(P0.x); w_[1]=f2bf(P0.y); w_[2]=f2bf(P0.z); w_[3]=f2bf(P0.w); \
    w_[4]=f2bf(P1.x); w_[5]=f2bf(P1.y); w_[6]=f2bf(P1.z); w_[7]=f2bf(P1.w); \
    *(short8*)&As[(slot) * 4096 + awoff] = w_; }

#define ISSUE_B(REG, tt) { \
    _Pragma("unroll") \
    for (int nf_ = 0; nf_ < 4; ++nf_) \
      REG[nf_] = *(const short8*)(bSrcR + (size_t)nf_ * 16 * H_ + (tt) * BK); }

  // One sub-step. ASLOT/reg-set selection compile-time within the x2-unrolled loop.
#define SUBSTEP(T, ASLOT, RI0, RI1, RW0, RW1, BCUR, BNXT) { \
    if ((T) + 2 < NSTEP) { ISSUE_SET(RI0, RI1, (T) + 2); } \
    if ((T) + 1 < NSTEP) { ISSUE_B(BNXT, (T) + 1); } \
    FENCE; \
    short8 af[4]; \
    _Pragma("unroll") \
    for (int mf = 0; mf < 4; ++mf) \
      af[mf] = *(const short8*)&As[(ASLOT) * 4096 + pA + mf * 512]; \
    _Pragma("unroll") \
    for (int nf = 0; nf < 4; ++nf) \
      _Pragma("unroll") \
      for (int mf = 0; mf < 4; ++mf) \
        acc[mf][nf] = __builtin_amdgcn_mfma_f32_16x16x32_bf16(af[mf], BCUR[nf], acc[mf][nf], 0, 0, 0); \
    FENCE; \
    if ((T) + 2 < NSTEP)      { asm volatile("s_waitcnt vmcnt(6)" ::: "memory"); } \
    else if ((T) + 1 < NSTEP) { asm volatile("s_waitcnt vmcnt(4)" ::: "memory"); } \
    if ((T) + 1 < NSTEP) { \
      WRITE_SET(RW0, RW1, ((T) + 1) & 1); \
      asm volatile("s_waitcnt lgkmcnt(0)" ::: "memory"); \
    } \
    FENCE; \
    __builtin_amdgcn_s_barrier(); }

  // ---- prologue: A(0)->X, A(1)->Y, B(0)->bX; write A(0) slot0 ----
  ISSUE_SET(aX0, aX1, 0);                       // 2 loads (oldest)
  ISSUE_SET(aY0, aY1, 1);                       // 2 loads
  ISSUE_B(bX, 0);                               // 4 loads
  asm volatile("s_waitcnt vmcnt(6)" ::: "memory");   // A(0) done
  WRITE_SET(aX0, aX1, 0);
  asm volatile("s_waitcnt lgkmcnt(0)" ::: "memory");
  FENCE;
  __builtin_amdgcn_s_barrier();

  for (int t = 0; t < NSTEP; t += 2) {
    // even: A-slot0; issue A(t+2)->X, write A(t+1) from Y; consume bX, load bY
    SUBSTEP(t,     0, aX0, aX1, aY0, aY1, bX, bY);
    // odd:  A-slot1; issue A(t+3)->Y, write A(t+2) from X; consume bY, load bX
    SUBSTEP(t + 1, 1, aY0, aY1, aX0, aX1, bY, bX);
  }

  // ---- epilogue: tanh(acc + b1q) * V, reduce over u ----
  __syncthreads();
  const int b_blk = bm >> 4;                 // 128-row tile never crosses a batch
  float bqv[4], vvv[4];
#pragma unroll
  for (int nf = 0; nf < 4; ++nf) {
    const int ug = u0 + wn * 64 + nf * 16 + l15;   // D col = lane&15
    bqv[nf] = b1q[b_blk * U_ + ug];
    vvv[nf] = V[ug];
  }
  float rp[4][4];
#pragma unroll
  for (int mf = 0; mf < 4; ++mf)
#pragma unroll
    for (int j = 0; j < 4; ++j) rp[mf][j] = 0.f;
#pragma unroll
  for (int nf = 0; nf < 4; ++nf)
#pragma unroll
    for (int mf = 0; mf < 4; ++mf) {
      const f32x4 c = acc[mf][nf];
#pragma unroll
      for (int j = 0; j < 4; ++j) {
        const float x = c[j] + bqv[nf];
        const float e = __expf(2.f * x);     // inf-safe tanh
        const float tt = 1.f - 2.f / (e + 1.f);
        rp[mf][j] += tt * vvv[nf];
      }
    }
#pragma unroll
  for (int mf = 0; mf < 4; ++mf)
#pragma unroll
    for (int j = 0; j < 4; ++j) {
      float v = rp[mf][j];
      v += __shfl_xor(v, 1);
      v += __shfl_xor(v, 2);
      v += __shfl_xor(v, 4);
      v += __shfl_xor(v, 8);
      rp[mf][j] = v;
    }
  if (l15 == 0) {
#pragma unroll
    for (int mf = 0; mf < 4; ++mf)
#pragma unroll
      for (int j = 0; j < 4; ++j)
        scorebuf[(wm * 64 + mf * 16 + l16 * 4 + j) * 4 + wn] = rp[mf][j];
  }
  __syncthreads();
  if (tid < BM) {
    const float s = scorebuf[tid * 4 + 0] + scorebuf[tid * 4 + 1] +
                    scorebuf[tid * 4 + 2] + scorebuf[tid * 4 + 3];
    score_part[(size_t)bn * (B_ * S_) + bm * BM + tid] = s;
  }
}

// ---------- softmax over S per batch (4 u-partials; bV shift-invariant -> dropped) ----------
__global__ void k_softmax(const float* __restrict__ sp, float* __restrict__ aw) {
  __shared__ float red[8];
  const int b = blockIdx.x, tid = threadIdx.x;   // 256 threads, 8 elems each
  const int BS = B_ * S_;
  float x[8];
  float m = -1e30f;
#pragma unroll
  for (int i = 0; i < 8; ++i) {
    const int s = b * S_ + tid + i * 256;
    x[i] = sp[s] + sp[BS + s] + sp[2 * BS + s] + sp[3 * BS + s];
    m = fmaxf(m, x[i]);
  }
#pragma unroll
  for (int off = 32; off; off >>= 1) m = fmaxf(m, __shfl_xor(m, off));
  if ((tid & 63) == 0) red[tid >> 6] = m;
  __syncthreads();
  m = fmaxf(fmaxf(red[0], red[1]), fmaxf(red[2], red[3]));
  float e[8];
  float sum = 0.f;
#pragma unroll
  for (int i = 0; i < 8; ++i) { e[i] = __expf(x[i] - m); sum += e[i]; }
#pragma unroll
  for (int off = 32; off; off >>= 1) sum += __shfl_xor(sum, off);
  __syncthreads();
  if ((tid & 63) == 0) red[4 + (tid >> 6)] = sum;
  __syncthreads();
  sum = red[4] + red[5] + red[6] + red[7];
  const float inv = 1.f / sum;
#pragma unroll
  for (int i = 0; i < 8; ++i) aw[b * S_ + tid + i * 256] = e[i] * inv;
}

// ---------- context: partial weighted sums over 64-row s-chunks (f32), then combine ----------
__global__ void k_ctx_partial(const float* __restrict__ values, const float* __restrict__ aw,
                              float* __restrict__ part) {
  __shared__ float a_s[64];
  const int b = blockIdx.y, sc = blockIdx.x, tid = threadIdx.x;  // 32 chunks x 64 s
  if (tid < 64) a_s[tid] = aw[b * S_ + sc * 64 + tid];
  __syncthreads();
  const float4* vp = (const float4*)values + (size_t)(b * S_ + sc * 64) * (H_ / 4) + tid;
  float4 acc = {0.f, 0.f, 0.f, 0.f};
#pragma unroll 4
  for (int i = 0; i < 64; ++i) {
    const float4 v = vp[(size_t)i * (H_ / 4)];
    const float a = a_s[i];
    acc.x += a * v.x; acc.y += a * v.y; acc.z += a * v.z; acc.w += a * v.w;
  }
  ((float4*)part)[(size_t)(b * 32 + sc) * (H_ / 4) + tid] = acc;
}

__global__ void k_ctx_combine(const float* __restrict__ part, float* __restrict__ ctx) {
  const int b = blockIdx.x, tid = threadIdx.x;
  float4 s = {0.f, 0.f, 0.f, 0.f};
#pragma unroll
  for (int c = 0; c < 32; ++c) {
    const float4 v = ((const float4*)part)[(size_t)(b * 32 + c) * (H_ / 4) + tid];
    s.x += v.x; s.y += v.y; s.z += v.z; s.w += v.w;
  }
  ((float4*)ctx)[b * (H_ / 4) + tid] = s;
}

extern "C" void kernel_launch(void* const* d_in, const int* in_sizes, int n_in,
                              void* d_out, int out_size, void* d_ws, size_t ws_size,
                              hipStream_t stream) {
  const float* query  = (const float*)d_in[0];
  const float* values = (const float*)d_in[1];
  const float* W1     = (const float*)d_in[2];
  const float* b1     = (const float*)d_in[3];
  const float* W2     = (const float*)d_in[4];
  const float* b2     = (const float*)d_in[5];
  const float* V      = (const float*)d_in[6];
  // d_in[7] = bV: softmax shift-invariant, affects neither output -> unused.

  char* ws = (char*)d_ws;
  unsigned short* W1T = (unsigned short*)ws;                                   // 2 MB  [U][H] bf16
  float* b1q   = (float*)(ws + 2u * 1024u * 1024u);                            // 128 KB [B][U]
  float* spart = (float*)(ws + 2u * 1024u * 1024u + 128u * 1024u);             // 1 MB  [4][B*S]
  float* qpart = (float*)(ws + 3u * 1024u * 1024u + 128u * 1024u);             // 1 MB  [8][B][U]
  float* cpart = (float*)(ws + 4u * 1024u * 1024u + 256u * 1024u);             // 4 MB  [B*32][H]

  float* aw  = (float*)d_out;        // [B,S,1]
  float* ctx = aw + B_ * S_;         // [B,H]

  k_transpose_w1<<<dim3(16, 16), dim3(64, 4), 0, stream>>>(W1, W1T);
  k_b1q_part<<<dim3(4, 8), dim3(256), 0, stream>>>(query, W2, qpart);
  k_b1q_comb<<<dim3(4, 32), dim3(256), 0, stream>>>(qpart, b1, b2, b1q);
  k_fused_score<<<dim3(2048), dim3(512), 0, stream>>>(values, W1T, b1q, V, spart);
  k_softmax<<<dim3(32), dim3(256), 0, stream>>>(spart, aw);
  k_ctx_partial<<<dim3(32, 32), dim3(256), 0, stream>>>(values, aw, cpart);
  k_ctx_combine<<<dim3(32), dim3(256), 0, stream>>>(cpart, ctx);
}

// Round 11
// 406.528 us; speedup vs baseline: 1.5532x; 1.5532x over previous
//
#include <hip/hip_runtime.h>
#include <hip/hip_bf16.h>
#include <stdint.h>

#define B_ 32
#define S_ 2048
#define H_ 1024
#define U_ 1024

typedef __attribute__((ext_vector_type(8))) short short8;
typedef __attribute__((ext_vector_type(4))) float f32x4;

#define AS1 __attribute__((address_space(1)))
#define AS3 __attribute__((address_space(3)))
#define FENCE __builtin_amdgcn_sched_barrier(0)

__device__ __forceinline__ unsigned short f2bf(float f) {
  unsigned int u = __float_as_uint(f);
  u += 0x7fffu + ((u >> 16) & 1u);   // RNE
  return (unsigned short)(u >> 16);
}

// ---------- prep 1: W1 [H][U] f32 -> W1T [U][H] bf16 ----------
__global__ void k_transpose_w1(const float* __restrict__ W1, unsigned short* __restrict__ W1T) {
  __shared__ float tile[64][65];
  const int tx = threadIdx.x, ty = threadIdx.y;
  const int u0 = blockIdx.x * 64, h0 = blockIdx.y * 64;
#pragma unroll
  for (int i = 0; i < 16; ++i) {
    int hl = ty + i * 4;
    tile[hl][tx] = W1[(size_t)(h0 + hl) * U_ + (u0 + tx)];
  }
  __syncthreads();
#pragma unroll
  for (int i = 0; i < 16; ++i) {
    int ul = ty + i * 4;
    W1T[(size_t)(u0 + ul) * H_ + (h0 + tx)] = f2bf(tile[tx][ul]);
  }
}

// ---------- prep 2a: qpart[hs][b][u] = sum_{h in strip hs} query[b][h]*W2[h][u] ----------
__global__ void k_b1q_part(const float* __restrict__ query, const float* __restrict__ W2,
                           float* __restrict__ qpart) {
  __shared__ float q_sh[32 * 128];
  const int u = blockIdx.x * 256 + threadIdx.x;
  const int hs = blockIdx.y;                       // 8 strips of 128
  for (int i = threadIdx.x; i < 4096; i += 256) {
    const int b = i >> 7, h = i & 127;
    q_sh[i] = query[b * H_ + hs * 128 + h];
  }
  __syncthreads();
  float acc[32];
#pragma unroll
  for (int b = 0; b < 32; ++b) acc[b] = 0.f;
  for (int h = 0; h < 128; ++h) {
    const float w = W2[(size_t)(hs * 128 + h) * U_ + u];
#pragma unroll
    for (int b = 0; b < 32; ++b) acc[b] += q_sh[b * 128 + h] * w;
  }
#pragma unroll
  for (int b = 0; b < 32; ++b) qpart[((size_t)hs * 32 + b) * U_ + u] = acc[b];
}

// ---------- prep 2b: b1q[b][u] = b1[u]+b2[u]+sum_hs qpart ----------
__global__ void k_b1q_comb(const float* __restrict__ qpart, const float* __restrict__ b1,
                           const float* __restrict__ b2, float* __restrict__ b1q) {
  const int u = blockIdx.x * 256 + threadIdx.x;
  const int b = blockIdx.y;
  float s = b1[u] + b2[u];
#pragma unroll
  for (int hs = 0; hs < 8; ++hs) s += qpart[((size_t)hs * 32 + b) * U_ + u];
  b1q[b * U_ + u] = s;
}

// ---------- fused GEMM+tanh+V: B JIT global->reg (L1/L2-hot), A-only LDS ----------
// Tile 128x256xBK32, 8 waves (2x4), wave 64x64, launch_bounds(512,4) -> 2 blocks/CU.
// Register budget (the r10 killer): acc 64 + B 16 (single JIT set) + A-issue 8
// (1-step) + af 16 + addr ~15 = ~119 < 128. LDS = As 2x8KB only: 40 KB/step/block
// LDS traffic (~470 cyc) < 620 cyc matrix -> matrix-pipe is the binding resource.
// Step t: load B(t)->regs (16 B/lane x4, rows L1/L2-hot; wm-pair dup absorbed by L1),
// then issue A(t+1) f32 (stays in flight through MFMA's vmcnt(2)-style wait),
// ds_read af, MFMA x16, write A(t+1)->As[^1] (loads landed during MFMA), lgkm0+barrier.
// A swizzle (r2-verified, 0 conflicts): chunk lc of row r at phys lc ^ ((r>>1)&3).
#define BM 128
#define BN 256
#define BK 32
#define NSTEP 32   // H_/BK

__global__ __launch_bounds__(512, 4)
void k_fused_score(const float* __restrict__ values,
                   const unsigned short* __restrict__ W1T,
                   const float* __restrict__ b1q, const float* __restrict__ V,
                   float* __restrict__ score_part) {
  __shared__ __align__(16) unsigned char smem[16384];
  unsigned short* As = (unsigned short*)smem;             // [2][128*32]
  float* scorebuf = (float*)smem;                          // alias post-loop

  const int tid = threadIdx.x;
  const int g = blockIdx.x;                  // 2048 = 512 bm x 4 bn
  const int seq = (g & 7) * 256 + (g >> 3);  // bijective XCD swizzle (2048 = 8*256)
  const int bn = seq & 3;
  const int bm = seq >> 2;

  const int lane = tid & 63, wid = tid >> 6;
  const int wm = wid >> 2, wn = wid & 3;     // 2 x 4 waves
  const int u0 = bn * BN;

  // A staging (regs): thread -> (row, logical chunk of 8 f32->bf16)
  const int arow = tid >> 2;                 // 0..127
  const int alc  = tid & 3;                  // logical chunk
  const int aplc = alc ^ ((arow >> 1) & 3);  // phys chunk (swizzled)
  const float* aSrcF = values + (size_t)(bm * BM + arow) * H_ + alc * 8;
  const int awoff = arow * 32 + aplc * 8;    // shorts, + slot*4096

  // fragment read swizzle (A)
  const int l15 = lane & 15, l16 = lane >> 4;
  const int fsq = ((l16 ^ ((lane >> 1) & 3)) << 3);   // shorts
  const int pA = (wm * 64 + l15) * 32 + fsq;          // + mf*512

  // B direct-load base: u = u0 + wn*64 + nf*16 + l15, k-chunk = l16
  const unsigned short* bSrcR = W1T + (size_t)(u0 + wn * 64 + l15) * H_ + l16 * 8;

  f32x4 acc[4][4];
#pragma unroll
  for (int mf = 0; mf < 4; ++mf)
#pragma unroll
    for (int nf = 0; nf < 4; ++nf) acc[mf][nf] = (f32x4){0.f, 0.f, 0.f, 0.f};

  float4 a0, a1;                             // single A-issue set

#define WRITE_A(slot) { \
    short8 w_; \
    w_[0]=f2bf(a0.x); w_[1]=f2bf(a0.y); w_[2]=f2bf(a0.z); w_[3]=f2bf(a0.w); \
    w_[4]=f2bf(a1.x); w_[5]=f2bf(a1.y); w_[6]=f2bf(a1.z); w_[7]=f2bf(a1.w); \
    *(short8*)&As[(slot) * 4096 + awoff] = w_; }

  // One step; ASLOT compile-time via x2 unroll.
#define STEP(T, ASLOT) { \
    short8 b0_ = *(const short8*)(bSrcR + (size_t)0 * 16 * H_ + (T) * BK); \
    short8 b1_ = *(const short8*)(bSrcR + (size_t)1 * 16 * H_ + (T) * BK); \
    short8 b2_ = *(const short8*)(bSrcR + (size_t)2 * 16 * H_ + (T) * BK); \
    short8 b3_ = *(const short8*)(bSrcR + (size_t)3 * 16 * H_ + (T) * BK); \
    if ((T) + 1 < NSTEP) { \
      const float4* p_ = (const float4*)(aSrcF + ((T) + 1) * BK); \
      a0 = p_[0]; a1 = p_[1]; \
    } \
    FENCE; \
    short8 af0_ = *(const short8*)&As[(ASLOT) * 4096 + pA + 0 * 512]; \
    short8 af1_ = *(const short8*)&As[(ASLOT) * 4096 + pA + 1 * 512]; \
    short8 af2_ = *(const short8*)&As[(ASLOT) * 4096 + pA + 2 * 512]; \
    short8 af3_ = *(const short8*)&As[(ASLOT) * 4096 + pA + 3 * 512]; \
    _Pragma("unroll") \
    for (int nf_ = 0; nf_ < 1; ++nf_) {} \
    acc[0][0] = __builtin_amdgcn_mfma_f32_16x16x32_bf16(af0_, b0_, acc[0][0], 0, 0, 0); \
    acc[1][0] = __builtin_amdgcn_mfma_f32_16x16x32_bf16(af1_, b0_, acc[1][0], 0, 0, 0); \
    acc[2][0] = __builtin_amdgcn_mfma_f32_16x16x32_bf16(af2_, b0_, acc[2][0], 0, 0, 0); \
    acc[3][0] = __builtin_amdgcn_mfma_f32_16x16x32_bf16(af3_, b0_, acc[3][0], 0, 0, 0); \
    acc[0][1] = __builtin_amdgcn_mfma_f32_16x16x32_bf16(af0_, b1_, acc[0][1], 0, 0, 0); \
    acc[1][1] = __builtin_amdgcn_mfma_f32_16x16x32_bf16(af1_, b1_, acc[1][1], 0, 0, 0); \
    acc[2][1] = __builtin_amdgcn_mfma_f32_16x16x32_bf16(af2_, b1_, acc[2][1], 0, 0, 0); \
    acc[3][1] = __builtin_amdgcn_mfma_f32_16x16x32_bf16(af3_, b1_, acc[3][1], 0, 0, 0); \
    acc[0][2] = __builtin_amdgcn_mfma_f32_16x16x32_bf16(af0_, b2_, acc[0][2], 0, 0, 0); \
    acc[1][2] = __builtin_amdgcn_mfma_f32_16x16x32_bf16(af1_, b2_, acc[1][2], 0, 0, 0); \
    acc[2][2] = __builtin_amdgcn_mfma_f32_16x16x32_bf16(af2_, b2_, acc[2][2], 0, 0, 0); \
    acc[3][2] = __builtin_amdgcn_mfma_f32_16x16x32_bf16(af3_, b2_, acc[3][2], 0, 0, 0); \
    acc[0][3] = __builtin_amdgcn_mfma_f32_16x16x32_bf16(af0_, b3_, acc[0][3], 0, 0, 0); \
    acc[1][3] = __builtin_amdgcn_mfma_f32_16x16x32_bf16(af1_, b3_, acc[1][3], 0, 0, 0); \
    acc[2][3] = __builtin_amdgcn_mfma_f32_16x16x32_bf16(af2_, b3_, acc[2][3], 0, 0, 0); \
    acc[3][3] = __builtin_amdgcn_mfma_f32_16x16x32_bf16(af3_, b3_, acc[3][3], 0, 0, 0); \
    FENCE; \
    if ((T) + 1 < NSTEP) { WRITE_A(((T) + 1) & 1); } \
    asm volatile("s_waitcnt lgkmcnt(0)" ::: "memory"); \
    FENCE; \
    __builtin_amdgcn_s_barrier(); }

  // ---- prologue: A(0)->regs->LDS slot0 ----
  {
    const float4* p_ = (const float4*)aSrcF;
    a0 = p_[0]; a1 = p_[1];
    asm volatile("s_waitcnt vmcnt(0)" ::: "memory");
    WRITE_A(0);
    asm volatile("s_waitcnt lgkmcnt(0)" ::: "memory");
    FENCE;
    __builtin_amdgcn_s_barrier();
  }

  for (int t = 0; t < NSTEP; t += 2) {
    STEP(t,     0);
    STEP(t + 1, 1);
  }

  // ---- epilogue: tanh(acc + b1q) * V, reduce over u ----
  __syncthreads();
  const int b_blk = bm >> 4;                 // 128-row tile never crosses a batch
  float bqv[4], vvv[4];
#pragma unroll
  for (int nf = 0; nf < 4; ++nf) {
    const int ug = u0 + wn * 64 + nf * 16 + l15;   // D col = lane&15
    bqv[nf] = b1q[b_blk * U_ + ug];
    vvv[nf] = V[ug];
  }
  float rp[4][4];
#pragma unroll
  for (int mf = 0; mf < 4; ++mf)
#pragma unroll
    for (int j = 0; j < 4; ++j) rp[mf][j] = 0.f;
#pragma unroll
  for (int nf = 0; nf < 4; ++nf)
#pragma unroll
    for (int mf = 0; mf < 4; ++mf) {
      const f32x4 c = acc[mf][nf];
#pragma unroll
      for (int j = 0; j < 4; ++j) {
        const float x = c[j] + bqv[nf];
        const float e = __expf(2.f * x);     // inf-safe tanh
        const float tt = 1.f - 2.f / (e + 1.f);
        rp[mf][j] += tt * vvv[nf];
      }
    }
#pragma unroll
  for (int mf = 0; mf < 4; ++mf)
#pragma unroll
    for (int j = 0; j < 4; ++j) {
      float v = rp[mf][j];
      v += __shfl_xor(v, 1);
      v += __shfl_xor(v, 2);
      v += __shfl_xor(v, 4);
      v += __shfl_xor(v, 8);
      rp[mf][j] = v;
    }
  if (l15 == 0) {
#pragma unroll
    for (int mf = 0; mf < 4; ++mf)
#pragma unroll
      for (int j = 0; j < 4; ++j)
        scorebuf[(wm * 64 + mf * 16 + l16 * 4 + j) * 4 + wn] = rp[mf][j];
  }
  __syncthreads();
  if (tid < BM) {
    const float s = scorebuf[tid * 4 + 0] + scorebuf[tid * 4 + 1] +
                    scorebuf[tid * 4 + 2] + scorebuf[tid * 4 + 3];
    score_part[(size_t)bn * (B_ * S_) + bm * BM + tid] = s;
  }
}

// ---------- softmax over S per batch (4 u-partials; bV shift-invariant -> dropped) ----------
__global__ void k_softmax(const float* __restrict__ sp, float* __restrict__ aw) {
  __shared__ float red[8];
  const int b = blockIdx.x, tid = threadIdx.x;   // 256 threads, 8 elems each
  const int BS = B_ * S_;
  float x[8];
  float m = -1e30f;
#pragma unroll
  for (int i = 0; i < 8; ++i) {
    const int s = b * S_ + tid + i * 256;
    x[i] = sp[s] + sp[BS + s] + sp[2 * BS + s] + sp[3 * BS + s];
    m = fmaxf(m, x[i]);
  }
#pragma unroll
  for (int off = 32; off; off >>= 1) m = fmaxf(m, __shfl_xor(m, off));
  if ((tid & 63) == 0) red[tid >> 6] = m;
  __syncthreads();
  m = fmaxf(fmaxf(red[0], red[1]), fmaxf(red[2], red[3]));
  float e[8];
  float sum = 0.f;
#pragma unroll
  for (int i = 0; i < 8; ++i) { e[i] = __expf(x[i] - m); sum += e[i]; }
#pragma unroll
  for (int off = 32; off; off >>= 1) sum += __shfl_xor(sum, off);
  __syncthreads();
  if ((tid & 63) == 0) red[4 + (tid >> 6)] = sum;
  __syncthreads();
  sum = red[4] + red[5] + red[6] + red[7];
  const float inv = 1.f / sum;
#pragma unroll
  for (int i = 0; i < 8; ++i) aw[b * S_ + tid + i * 256] = e[i] * inv;
}

// ---------- context: partial weighted sums over 64-row s-chunks (f32), then combine ----------
__global__ void k_ctx_partial(const float* __restrict__ values, const float* __restrict__ aw,
                              float* __restrict__ part) {
  __shared__ float a_s[64];
  const int b = blockIdx.y, sc = blockIdx.x, tid = threadIdx.x;  // 32 chunks x 64 s
  if (tid < 64) a_s[tid] = aw[b * S_ + sc * 64 + tid];
  __syncthreads();
  const float4* vp = (const float4*)values + (size_t)(b * S_ + sc * 64) * (H_ / 4) + tid;
  float4 acc = {0.f, 0.f, 0.f, 0.f};
#pragma unroll 4
  for (int i = 0; i < 64; ++i) {
    const float4 v = vp[(size_t)i * (H_ / 4)];
    const float a = a_s[i];
    acc.x += a * v.x; acc.y += a * v.y; acc.z += a * v.z; acc.w += a * v.w;
  }
  ((float4*)part)[(size_t)(b * 32 + sc) * (H_ / 4) + tid] = acc;
}

__global__ void k_ctx_combine(const float* __restrict__ part, float* __restrict__ ctx) {
  const int b = blockIdx.x, tid = threadIdx.x;
  float4 s = {0.f, 0.f, 0.f, 0.f};
#pragma unroll
  for (int c = 0; c < 32; ++c) {
    const float4 v = ((const float4*)part)[(size_t)(b * 32 + c) * (H_ / 4) + tid];
    s.x += v.x; s.y += v.y; s.z += v.z; s.w += v.w;
  }
  ((float4*)ctx)[b * (H_ / 4) + tid] = s;
}

extern "C" void kernel_launch(void* const* d_in, const int* in_sizes, int n_in,
                              void* d_out, int out_size, void* d_ws, size_t ws_size,
                              hipStream_t stream) {
  const float* query  = (const float*)d_in[0];
  const float* values = (const float*)d_in[1];
  const float* W1     = (const float*)d_in[2];
  const float* b1     = (const float*)d_in[3];
  const float* W2     = (const float*)d_in[4];
  const float* b2     = (const float*)d_in[5];
  const float* V      = (const float*)d_in[6];
  // d_in[7] = bV: softmax shift-invariant, affects neither output -> unused.

  char* ws = (char*)d_ws;
  unsigned short* W1T = (unsigned short*)ws;                                   // 2 MB  [U][H] bf16
  float* b1q   = (float*)(ws + 2u * 1024u * 1024u);                            // 128 KB [B][U]
  float* spart = (float*)(ws + 2u * 1024u * 1024u + 128u * 1024u);             // 1 MB  [4][B*S]
  float* qpart = (float*)(ws + 3u * 1024u * 1024u + 128u * 1024u);             // 1 MB  [8][B][U]
  float* cpart = (float*)(ws + 4u * 1024u * 1024u + 256u * 1024u);             // 4 MB  [B*32][H]

  float* aw  = (float*)d_out;        // [B,S,1]
  float* ctx = aw + B_ * S_;         // [B,H]

  k_transpose_w1<<<dim3(16, 16), dim3(64, 4), 0, stream>>>(W1, W1T);
  k_b1q_part<<<dim3(4, 8), dim3(256), 0, stream>>>(query, W2, qpart);
  k_b1q_comb<<<dim3(4, 32), dim3(256), 0, stream>>>(qpart, b1, b2, b1q);
  k_fused_score<<<dim3(2048), dim3(512), 0, stream>>>(values, W1T, b1q, V, spart);
  k_softmax<<<dim3(32), dim3(256), 0, stream>>>(spart, aw);
  k_ctx_partial<<<dim3(32, 32), dim3(256), 0, stream>>>(values, aw, cpart);
  k_ctx_combine<<<dim3(32), dim3(256), 0, stream>>>(cpart, ctx);
}

// Round 13
// 305.998 us; speedup vs baseline: 2.0635x; 1.3285x over previous
//
#include <hip/hip_runtime.h>
#include <hip/hip_bf16.h>
#include <stdint.h>

#define B_ 32
#define S_ 2048
#define H_ 1024
#define U_ 1024

typedef __attribute__((ext_vector_type(8))) short short8;
typedef __attribute__((ext_vector_type(4))) float f32x4;

#define AS1 __attribute__((address_space(1)))
#define AS3 __attribute__((address_space(3)))
#define FENCE __builtin_amdgcn_sched_barrier(0)

__device__ __forceinline__ unsigned short f2bf(float f) {
  unsigned int u = __float_as_uint(f);
  u += 0x7fffu + ((u >> 16) & 1u);   // RNE
  return (unsigned short)(u >> 16);
}
__device__ __forceinline__ float bf2f(unsigned short s) {
  return __uint_as_float(((unsigned int)s) << 16);
}

// ---------- prep 0: values f32 -> bf16 copy ----------
__global__ void k_cvt(const float* __restrict__ v, unsigned short* __restrict__ o) {
  const size_t n = (size_t)B_ * S_ * H_;
  const size_t stride = (size_t)gridDim.x * blockDim.x * 8;
  for (size_t i = ((size_t)blockIdx.x * blockDim.x + threadIdx.x) * 8; i < n; i += stride) {
    float4 a = *(const float4*)(v + i), b = *(const float4*)(v + i + 4);
    short8 w;
    w[0]=f2bf(a.x); w[1]=f2bf(a.y); w[2]=f2bf(a.z); w[3]=f2bf(a.w);
    w[4]=f2bf(b.x); w[5]=f2bf(b.y); w[6]=f2bf(b.z); w[7]=f2bf(b.w);
    *(short8*)(o + i) = w;
  }
}

// ---------- prep 1: W1 [H][U] f32 -> W1T [U][H] bf16 ----------
__global__ void k_transpose_w1(const float* __restrict__ W1, unsigned short* __restrict__ W1T) {
  __shared__ float tile[64][65];
  const int tx = threadIdx.x, ty = threadIdx.y;
  const int u0 = blockIdx.x * 64, h0 = blockIdx.y * 64;
#pragma unroll
  for (int i = 0; i < 16; ++i) {
    int hl = ty + i * 4;
    tile[hl][tx] = W1[(size_t)(h0 + hl) * U_ + (u0 + tx)];
  }
  __syncthreads();
#pragma unroll
  for (int i = 0; i < 16; ++i) {
    int ul = ty + i * 4;
    W1T[(size_t)(u0 + ul) * H_ + (h0 + tx)] = f2bf(tile[tx][ul]);
  }
}

// ---------- prep 2a: qpart[hs][b][u] = sum_{h in strip hs} query[b][h]*W2[h][u] ----------
__global__ void k_b1q_part(const float* __restrict__ query, const float* __restrict__ W2,
                           float* __restrict__ qpart) {
  __shared__ float q_sh[32 * 128];
  const int u = blockIdx.x * 256 + threadIdx.x;
  const int hs = blockIdx.y;                       // 8 strips of 128
  for (int i = threadIdx.x; i < 4096; i += 256) {
    const int b = i >> 7, h = i & 127;
    q_sh[i] = query[b * H_ + hs * 128 + h];
  }
  __syncthreads();
  float acc[32];
#pragma unroll
  for (int b = 0; b < 32; ++b) acc[b] = 0.f;
  for (int h = 0; h < 128; ++h) {
    const float w = W2[(size_t)(hs * 128 + h) * U_ + u];
#pragma unroll
    for (int b = 0; b < 32; ++b) acc[b] += q_sh[b * 128 + h] * w;
  }
#pragma unroll
  for (int b = 0; b < 32; ++b) qpart[((size_t)hs * 32 + b) * U_ + u] = acc[b];
}

// ---------- prep 2b: b1q[b][u] = b1[u]+b2[u]+sum_hs qpart ----------
__global__ void k_b1q_comb(const float* __restrict__ qpart, const float* __restrict__ b1,
                           const float* __restrict__ b2, float* __restrict__ b1q) {
  const int u = blockIdx.x * 256 + threadIdx.x;
  const int b = blockIdx.y;
  float s = b1[u] + b2[u];
#pragma unroll
  for (int hs = 0; hs < 8; ++hs) s += qpart[((size_t)hs * 32 + b) * U_ + u];
  b1q[b * U_ + u] = s;
}

// ---------- fused GEMM+tanh+V: r7 3-slot DMA pipeline, unrolled x3, offset-0 staging ----------
// Tile 128x256xBK32, 8 waves (2x4), 2 blocks/CU, LDS 72 KB (As[3] 24K + Bs[3] 48K).
// Step t: stage tile t+2 (3 gl_lds at precomputed address, offset param 0 — the r12
// imm-offset experiment produced NaN; unverified field, reverted), frag-read slot t%3,
// 16 MFMA, vmcnt(3) (retires stage t+1, keeps t+2 in flight), s_barrier. Slot
// indices/LDS bases compile-time via x3 unroll; src ptrs advance once per 3 steps;
// constant k-offsets left for the compiler to fold legally. Never vmcnt(0) mid-loop.
// Swizzle (r2-verified, 0 conflicts): logical chunk lc of row r at phys lc^((r>>1)&3).
#define BM 128
#define BN 256
#define BK 32
#define NSTEP 32   // H_/BK

__global__ __launch_bounds__(512, 4)
void k_fused_score(const unsigned short* __restrict__ vbf,
                   const unsigned short* __restrict__ W1T,
                   const float* __restrict__ b1q, const float* __restrict__ V,
                   float* __restrict__ score_part) {
  __shared__ __align__(16) unsigned char smem[73728];
  unsigned short* As = (unsigned short*)smem;             // [3][128*32] = 24 KB
  unsigned short* Bs = (unsigned short*)(smem + 24576);   // [3][256*32] = 48 KB
  float* scorebuf = (float*)smem;                          // alias post-loop

  const int tid = threadIdx.x;
  const int g = blockIdx.x;                  // 2048 = 512 bm x 4 bn
  const int seq = (g & 7) * 256 + (g >> 3);  // bijective XCD swizzle (2048 = 8*256)
  const int bn = seq & 3;
  const int bm = seq >> 2;

  const int lane = tid & 63, wid = tid >> 6;
  const int wm = wid >> 2, wn = wid & 3;     // 2 x 4 waves
  const int u0 = bn * BN;

  // staging: pre-swizzled source chunk (involution, r2-verified)
  const int arow = tid >> 2;
  const int alc = (tid & 3) ^ ((arow >> 1) & 3);
  const unsigned short* pa  = vbf + (size_t)(bm * BM + arow) * H_ + alc * 8;
  const unsigned short* pb0 = W1T + (size_t)(u0 + arow) * H_ + alc * 8;
  const unsigned short* pb1 = pb0 + (size_t)128 * H_;

  // fragment read swizzle
  const int l15 = lane & 15, l16 = lane >> 4;
  const int fsq = ((l16 ^ ((lane >> 1) & 3)) << 3);   // shorts
  const int pA = (wm * 64 + l15) * 32 + fsq;          // + mf*512
  const int pB = (wn * 64 + l15) * 32 + fsq;          // + nf*512

  f32x4 acc[4][4];
#pragma unroll
  for (int mf = 0; mf < 4; ++mf)
#pragma unroll
    for (int nf = 0; nf < 4; ++nf) acc[mf][nf] = (f32x4){0.f, 0.f, 0.f, 0.f};

  // stage tile at pa/pb + KOFF (shorts) into compile-time slot; offset param 0
#define STAGE_K(SLOT, KOFF) { \
    __builtin_amdgcn_global_load_lds((const AS1 void*)(pa + (KOFF)),  \
        (AS3 void*)&As[(SLOT) * 4096 + tid * 8], 16, 0, 0); \
    __builtin_amdgcn_global_load_lds((const AS1 void*)(pb0 + (KOFF)), \
        (AS3 void*)&Bs[(SLOT) * 8192 + tid * 8], 16, 0, 0); \
    __builtin_amdgcn_global_load_lds((const AS1 void*)(pb1 + (KOFF)), \
        (AS3 void*)&Bs[(SLOT) * 8192 + 4096 + tid * 8], 16, 0, 0); }

#define COMPUTE(SC) { \
    short8 af[4], bv[4]; \
    _Pragma("unroll") \
    for (int mf = 0; mf < 4; ++mf) \
      af[mf] = *(const short8*)&As[(SC) * 4096 + pA + mf * 512]; \
    _Pragma("unroll") \
    for (int nf = 0; nf < 4; ++nf) \
      bv[nf] = *(const short8*)&Bs[(SC) * 8192 + pB + nf * 512]; \
    _Pragma("unroll") \
    for (int nf = 0; nf < 4; ++nf) \
      _Pragma("unroll") \
      for (int mf = 0; mf < 4; ++mf) \
        acc[mf][nf] = __builtin_amdgcn_mfma_f32_16x16x32_bf16(af[mf], bv[nf], acc[mf][nf], 0, 0, 0); }

#define SUBSTEP(SC, SN, KOFF) { \
    STAGE_K(SN, KOFF); \
    FENCE; \
    COMPUTE(SC); \
    FENCE; \
    asm volatile("s_waitcnt vmcnt(3)" ::: "memory"); \
    FENCE; \
    __builtin_amdgcn_s_barrier(); }

  // ---- prologue: stage tiles 0,1 into slots 0,1; wait tile 0 only ----
  STAGE_K(0, 0);
  STAGE_K(1, 32);
  asm volatile("s_waitcnt vmcnt(3)" ::: "memory");
  FENCE;
  __builtin_amdgcn_s_barrier();

  // ---- main: t = 0..29, unrolled x3 (slots 0,1,2 compile-time) ----
  for (int it = 0; it < 10; ++it) {
    SUBSTEP(0, 2, 64);     // t=3it:   compute slot0, stage tile t+2 -> slot2
    SUBSTEP(1, 0, 96);     // t=3it+1: compute slot1, stage tile t+3 -> slot0
    SUBSTEP(2, 1, 128);    // t=3it+2: compute slot2, stage tile t+4 -> slot1
    pa += 96; pb0 += 96; pb1 += 96;      // advance 3 tiles (shorts)
  }
  // ---- tail: t=30 (slot0, drain stage31), t=31 (slot1) ----
  {
    COMPUTE(0);
    FENCE;
    asm volatile("s_waitcnt vmcnt(0)" ::: "memory");
    FENCE;
    __builtin_amdgcn_s_barrier();
    COMPUTE(1);
  }

  // ---- epilogue: tanh(acc + b1q) * V, reduce over u ----
  __syncthreads();
  const int b_blk = bm >> 4;                 // 128-row tile never crosses a batch
  float bqv[4], vvv[4];
#pragma unroll
  for (int nf = 0; nf < 4; ++nf) {
    const int ug = u0 + wn * 64 + nf * 16 + l15;   // D col = lane&15
    bqv[nf] = b1q[b_blk * U_ + ug];
    vvv[nf] = V[ug];
  }
  float rp[4][4];
#pragma unroll
  for (int mf = 0; mf < 4; ++mf)
#pragma unroll
    for (int j = 0; j < 4; ++j) rp[mf][j] = 0.f;
#pragma unroll
  for (int nf = 0; nf < 4; ++nf)
#pragma unroll
    for (int mf = 0; mf < 4; ++mf) {
      const f32x4 c = acc[mf][nf];
#pragma unroll
      for (int j = 0; j < 4; ++j) {
        const float x = c[j] + bqv[nf];
        const float e = __expf(2.f * x);     // inf-safe tanh
        const float tt = 1.f - 2.f / (e + 1.f);
        rp[mf][j] += tt * vvv[nf];
      }
    }
#pragma unroll
  for (int mf = 0; mf < 4; ++mf)
#pragma unroll
    for (int j = 0; j < 4; ++j) {
      float v = rp[mf][j];
      v += __shfl_xor(v, 1);
      v += __shfl_xor(v, 2);
      v += __shfl_xor(v, 4);
      v += __shfl_xor(v, 8);
      rp[mf][j] = v;
    }
  if (l15 == 0) {
#pragma unroll
    for (int mf = 0; mf < 4; ++mf)
#pragma unroll
      for (int j = 0; j < 4; ++j)
        scorebuf[(wm * 64 + mf * 16 + l16 * 4 + j) * 4 + wn] = rp[mf][j];
  }
  __syncthreads();
  if (tid < BM) {
    const float s = scorebuf[tid * 4 + 0] + scorebuf[tid * 4 + 1] +
                    scorebuf[tid * 4 + 2] + scorebuf[tid * 4 + 3];
    score_part[(size_t)bn * (B_ * S_) + bm * BM + tid] = s;
  }
}

// ---------- softmax over S per batch (4 u-partials; bV shift-invariant -> dropped) ----------
__global__ void k_softmax(const float* __restrict__ sp, float* __restrict__ aw) {
  __shared__ float red[8];
  const int b = blockIdx.x, tid = threadIdx.x;   // 256 threads, 8 elems each
  const int BS = B_ * S_;
  float x[8];
  float m = -1e30f;
#pragma unroll
  for (int i = 0; i < 8; ++i) {
    const int s = b * S_ + tid + i * 256;
    x[i] = sp[s] + sp[BS + s] + sp[2 * BS + s] + sp[3 * BS + s];
    m = fmaxf(m, x[i]);
  }
#pragma unroll
  for (int off = 32; off; off >>= 1) m = fmaxf(m, __shfl_xor(m, off));
  if ((tid & 63) == 0) red[tid >> 6] = m;
  __syncthreads();
  m = fmaxf(fmaxf(red[0], red[1]), fmaxf(red[2], red[3]));
  float e[8];
  float sum = 0.f;
#pragma unroll
  for (int i = 0; i < 8; ++i) { e[i] = __expf(x[i] - m); sum += e[i]; }
#pragma unroll
  for (int off = 32; off; off >>= 1) sum += __shfl_xor(sum, off);
  __syncthreads();
  if ((tid & 63) == 0) red[4 + (tid >> 6)] = sum;
  __syncthreads();
  sum = red[4] + red[5] + red[6] + red[7];
  const float inv = 1.f / sum;
#pragma unroll
  for (int i = 0; i < 8; ++i) aw[b * S_ + tid + i * 256] = e[i] * inv;
}

// ---------- context: partial weighted sums over s-chunks (bf16 values), then combine ----------
__global__ void k_ctx_partial(const unsigned short* __restrict__ vbf, const float* __restrict__ aw,
                              float* __restrict__ part) {
  __shared__ float a_s[128];
  const int b = blockIdx.y, sc = blockIdx.x, tid = threadIdx.x;  // 16 chunks x 128 s
  if (tid < 128) a_s[tid] = aw[b * S_ + sc * 128 + tid];
  __syncthreads();
  const unsigned short* vp = vbf + (size_t)(b * S_ + sc * 128) * H_ + tid * 4;
  float4 acc = {0.f, 0.f, 0.f, 0.f};
#pragma unroll 4
  for (int i = 0; i < 128; ++i) {
    const ushort4 v = *(const ushort4*)(vp + (size_t)i * H_);
    const float a = a_s[i];
    acc.x += a * bf2f(v.x); acc.y += a * bf2f(v.y);
    acc.z += a * bf2f(v.z); acc.w += a * bf2f(v.w);
  }
  ((float4*)part)[(size_t)(b * 16 + sc) * (H_ / 4) + tid] = acc;
}

__global__ void k_ctx_combine(const float* __restrict__ part, float* __restrict__ ctx) {
  const int b = blockIdx.x, tid = threadIdx.x;
  float4 s = {0.f, 0.f, 0.f, 0.f};
#pragma unroll
  for (int c = 0; c < 16; ++c) {
    const float4 v = ((const float4*)part)[(size_t)(b * 16 + c) * (H_ / 4) + tid];
    s.x += v.x; s.y += v.y; s.z += v.z; s.w += v.w;
  }
  ((float4*)ctx)[b * (H_ / 4) + tid] = s;
}

extern "C" void kernel_launch(void* const* d_in, const int* in_sizes, int n_in,
                              void* d_out, int out_size, void* d_ws, size_t ws_size,
                              hipStream_t stream) {
  const float* query  = (const float*)d_in[0];
  const float* values = (const float*)d_in[1];
  const float* W1     = (const float*)d_in[2];
  const float* b1     = (const float*)d_in[3];
  const float* W2     = (const float*)d_in[4];
  const float* b2     = (const float*)d_in[5];
  const float* V      = (const float*)d_in[6];
  // d_in[7] = bV: softmax shift-invariant, affects neither output -> unused.

  char* ws = (char*)d_ws;
  unsigned short* W1T = (unsigned short*)ws;                                   // 2 MB  [U][H] bf16
  float* b1q   = (float*)(ws + 2u * 1024u * 1024u);                            // 128 KB [B][U]
  float* spart = (float*)(ws + 2u * 1024u * 1024u + 128u * 1024u);             // 1 MB  [4][B*S]
  float* cpart = (float*)(ws + 3u * 1024u * 1024u + 128u * 1024u);             // 2 MB  [B*16][H]
  float* qpart = (float*)(ws + 5u * 1024u * 1024u + 128u * 1024u);             // 1 MB  [8][B][U]
  unsigned short* vbf = (unsigned short*)(ws + 8u * 1024u * 1024u);            // 128 MB [B*S][H] bf16

  float* aw  = (float*)d_out;        // [B,S,1]
  float* ctx = aw + B_ * S_;         // [B,H]

  k_transpose_w1<<<dim3(16, 16), dim3(64, 4), 0, stream>>>(W1, W1T);
  k_b1q_part<<<dim3(4, 8), dim3(256), 0, stream>>>(query, W2, qpart);
  k_b1q_comb<<<dim3(4, 32), dim3(256), 0, stream>>>(qpart, b1, b2, b1q);
  k_cvt<<<dim3(2048), dim3(256), 0, stream>>>(values, vbf);
  k_fused_score<<<dim3(2048), dim3(512), 0, stream>>>(vbf, W1T, b1q, V, spart);
  k_softmax<<<dim3(32), dim3(256), 0, stream>>>(spart, aw);
  k_ctx_partial<<<dim3(16, 32), dim3(256), 0, stream>>>(vbf, aw, cpart);
  k_ctx_combine<<<dim3(32), dim3(256), 0, stream>>>(cpart, ctx);
}

// Round 15
// 292.549 us; speedup vs baseline: 2.1584x; 1.0460x over previous
//
#include <hip/hip_runtime.h>
#include <hip/hip_bf16.h>
#include <stdint.h>

#define B_ 32
#define S_ 2048
#define H_ 1024
#define U_ 1024

typedef __attribute__((ext_vector_type(8))) short short8;
typedef __attribute__((ext_vector_type(4))) float f32x4;

#define AS1 __attribute__((address_space(1)))
#define AS3 __attribute__((address_space(3)))
#define FENCE __builtin_amdgcn_sched_barrier(0)
#define LGKM0 asm volatile("s_waitcnt lgkmcnt(0)" ::: "memory")
#define VMC4  asm volatile("s_waitcnt vmcnt(4)" ::: "memory")

__device__ __forceinline__ unsigned short f2bf(float f) {
  unsigned int u = __float_as_uint(f);
  u += 0x7fffu + ((u >> 16) & 1u);   // RNE
  return (unsigned short)(u >> 16);
}
__device__ __forceinline__ float bf2f(unsigned short s) {
  return __uint_as_float(((unsigned int)s) << 16);
}

// ---------- prep 0: values f32 -> bf16 copy ----------
__global__ void k_cvt(const float* __restrict__ v, unsigned short* __restrict__ o) {
  const size_t n = (size_t)B_ * S_ * H_;
  const size_t stride = (size_t)gridDim.x * blockDim.x * 8;
  for (size_t i = ((size_t)blockIdx.x * blockDim.x + threadIdx.x) * 8; i < n; i += stride) {
    float4 a = *(const float4*)(v + i), b = *(const float4*)(v + i + 4);
    short8 w;
    w[0]=f2bf(a.x); w[1]=f2bf(a.y); w[2]=f2bf(a.z); w[3]=f2bf(a.w);
    w[4]=f2bf(b.x); w[5]=f2bf(b.y); w[6]=f2bf(b.z); w[7]=f2bf(b.w);
    *(short8*)(o + i) = w;
  }
}

// ---------- prep 1: W1 [H][U] f32 -> W1T [U][H] bf16 ----------
__global__ void k_transpose_w1(const float* __restrict__ W1, unsigned short* __restrict__ W1T) {
  __shared__ float tile[64][65];
  const int tx = threadIdx.x, ty = threadIdx.y;
  const int u0 = blockIdx.x * 64, h0 = blockIdx.y * 64;
#pragma unroll
  for (int i = 0; i < 16; ++i) {
    int hl = ty + i * 4;
    tile[hl][tx] = W1[(size_t)(h0 + hl) * U_ + (u0 + tx)];
  }
  __syncthreads();
#pragma unroll
  for (int i = 0; i < 16; ++i) {
    int ul = ty + i * 4;
    W1T[(size_t)(u0 + ul) * H_ + (h0 + tx)] = f2bf(tile[tx][ul]);
  }
}

// ---------- prep 2a: qpart[hs][b][u] = sum_{h in strip hs} query[b][h]*W2[h][u] ----------
__global__ void k_b1q_part(const float* __restrict__ query, const float* __restrict__ W2,
                           float* __restrict__ qpart) {
  __shared__ float q_sh[32 * 128];
  const int u = blockIdx.x * 256 + threadIdx.x;
  const int hs = blockIdx.y;                       // 8 strips of 128
  for (int i = threadIdx.x; i < 4096; i += 256) {
    const int b = i >> 7, h = i & 127;
    q_sh[i] = query[b * H_ + hs * 128 + h];
  }
  __syncthreads();
  float acc[32];
#pragma unroll
  for (int b = 0; b < 32; ++b) acc[b] = 0.f;
  for (int h = 0; h < 128; ++h) {
    const float w = W2[(size_t)(hs * 128 + h) * U_ + u];
#pragma unroll
    for (int b = 0; b < 32; ++b) acc[b] += q_sh[b * 128 + h] * w;
  }
#pragma unroll
  for (int b = 0; b < 32; ++b) qpart[((size_t)hs * 32 + b) * U_ + u] = acc[b];
}

// ---------- prep 2b: b1q[b][u] = b1[u]+b2[u]+sum_hs qpart ----------
__global__ void k_b1q_comb(const float* __restrict__ qpart, const float* __restrict__ b1,
                           const float* __restrict__ b2, float* __restrict__ b1q) {
  const int u = blockIdx.x * 256 + threadIdx.x;
  const int b = blockIdx.y;
  float s = b1[u] + b2[u];
#pragma unroll
  for (int hs = 0; hs < 8; ++hs) s += qpart[((size_t)hs * 32 + b) * U_ + u];
  b1q[b * U_ + u] = s;
}

// ---------- fused GEMM+tanh+V: m201-faithful 8-phase, 256x256xBK64, 8 waves ----------
// Wave-tile 128x64 (acc[8][4]); LDS 128 KB = per-op 2 dbuf x [256r][64c] bf16.
// Iter i computes K-tiles t=2i (dbuf0, phases p1-4) and t+1 (dbuf1, p5-8).
// One half-tile (2 gl_lds) staged per phase: p1:Ah0(t+1) p2:Ah1(t+1) p3:Bh0(t+2)
// p4:Bh1(t+2)+vmcnt(4) p5:Ah0(t+2) p6:Ah1(t+2) p7:Bh0(t+3) p8:Bh1(t+3)+vmcnt(4).
// FIFO invariant: each vmcnt(4) retires exactly the loads the NEXT 4 phases read,
// and every stage targets a region whose reads finished >=1 phase earlier (tail
// clamps re-stage tile 15 into dead/identical regions - harmless). Never vmcnt(0)
// mid-loop. Swizzle: 8 chunks of 16B/row, phys = logical ^ (row&7) (2-way = free).
// r14 NaN bug: STAGEH multiplied the (already-shorts) TK by 64 again -> staged
// wrong/out-of-bounds rows. Fixed: TK added directly in shorts.
#define BMT 256
#define BNT 256
#define NKT 16   // K-tiles of 64

__global__ __launch_bounds__(512, 2)
void k_fused_score(const unsigned short* __restrict__ vbf,
                   const unsigned short* __restrict__ W1T,
                   const float* __restrict__ b1q, const float* __restrict__ V,
                   float* __restrict__ score_part) {
  __shared__ __align__(16) unsigned char smem[131072];
  unsigned short* Ash = (unsigned short*)smem;            // [2][256*64]
  unsigned short* Bsh = (unsigned short*)(smem + 65536);  // [2][256*64]
  float* scorebuf = (float*)smem;                          // alias post-loop

  const int tid = threadIdx.x;
  const int g = blockIdx.x;                  // 1024 = 256 bm x 4 bn
  const int seq = (g & 7) * 128 + (g >> 3);  // bijective XCD swizzle (1024 = 8*128)
  const int bn = seq & 3;
  const int bm = seq >> 2;

  const int lane = tid & 63, wid = tid >> 6;
  const int wm = wid >> 2, wn = wid & 3;     // 2M x 4N waves
  const int u0 = bn * BNT;

  // ---- staging addressing (gl_lds linear dest; pre-swizzled source) ----
  const int r0 = tid >> 3;                   // 0..63
  const int c0 = tid & 7;
  const int lc = c0 ^ (r0 & 7);              // logical source chunk (j-invariant: 64%8==0)
  const unsigned short* paS = vbf + (size_t)(bm * BMT + r0) * H_ + lc * 8;
  const unsigned short* pbS = W1T + (size_t)(u0 + r0) * H_ + lc * 8;
  const int dOff = tid * 16;                 // byte offset within (dbuf,half,j) region

  // ---- fragment read offsets (shorts): row*64 + (chunk^l7)*8 ----
  const int l15 = lane & 15, l16 = lane >> 4, l7 = lane & 7;
  const int pAk0 = (wm * 128 + l15) * 64 + ((0 + l16) ^ l7) * 8;   // + mf*1024 (+ d*16384)
  const int pAk1 = (wm * 128 + l15) * 64 + ((4 + l16) ^ l7) * 8;
  const int pBk0 = (wn * 64 + l15) * 64 + ((0 + l16) ^ l7) * 8;    // + nf*1024
  const int pBk1 = (wn * 64 + l15) * 64 + ((4 + l16) ^ l7) * 8;

  f32x4 acc[8][4];
#pragma unroll
  for (int mf = 0; mf < 8; ++mf)
#pragma unroll
    for (int nf = 0; nf < 4; ++nf) acc[mf][nf] = (f32x4){0.f, 0.f, 0.f, 0.f};

  short8 af0, af1, af2, af3;                 // mf-pair x kk
  short8 bv[4][2];                           // nf x kk, loaded at p1/p5

  // stage one half-tile: OP 0=A 1=B, half H, K-offset TK in SHORTS (t*64), dbuf D
#define STAGEH(OP, D, H, TK) { \
    const unsigned short* s0_ = ((OP) ? pbS : paS) + (size_t)(H) * 128 * H_ + (TK); \
    const unsigned short* s1_ = s0_ + (size_t)64 * H_; \
    unsigned char* dst_ = smem + (OP) * 65536 + (D) * 32768 + (H) * 16384 + dOff; \
    __builtin_amdgcn_global_load_lds((const AS1 void*)s0_, (AS3 void*)dst_, 16, 0, 0); \
    __builtin_amdgcn_global_load_lds((const AS1 void*)s1_, (AS3 void*)(dst_ + 8192), 16, 0, 0); }

#define READ_AF(D, Q) { \
    af0 = *(const short8*)&Ash[(D) * 16384 + (2*(Q)+0) * 1024 + pAk0]; \
    af1 = *(const short8*)&Ash[(D) * 16384 + (2*(Q)+0) * 1024 + pAk1]; \
    af2 = *(const short8*)&Ash[(D) * 16384 + (2*(Q)+1) * 1024 + pAk0]; \
    af3 = *(const short8*)&Ash[(D) * 16384 + (2*(Q)+1) * 1024 + pAk1]; }

#define READ_BV(D) { \
    _Pragma("unroll") \
    for (int nf_ = 0; nf_ < 4; ++nf_) { \
      bv[nf_][0] = *(const short8*)&Bsh[(D) * 16384 + nf_ * 1024 + pBk0]; \
      bv[nf_][1] = *(const short8*)&Bsh[(D) * 16384 + nf_ * 1024 + pBk1]; } }

#define MFMA16(Q) { \
    __builtin_amdgcn_s_setprio(1); \
    _Pragma("unroll") \
    for (int nf_ = 0; nf_ < 4; ++nf_) { \
      acc[2*(Q)+0][nf_] = __builtin_amdgcn_mfma_f32_16x16x32_bf16(af0, bv[nf_][0], acc[2*(Q)+0][nf_], 0, 0, 0); \
      acc[2*(Q)+1][nf_] = __builtin_amdgcn_mfma_f32_16x16x32_bf16(af2, bv[nf_][0], acc[2*(Q)+1][nf_], 0, 0, 0); \
      acc[2*(Q)+0][nf_] = __builtin_amdgcn_mfma_f32_16x16x32_bf16(af1, bv[nf_][1], acc[2*(Q)+0][nf_], 0, 0, 0); \
      acc[2*(Q)+1][nf_] = __builtin_amdgcn_mfma_f32_16x16x32_bf16(af3, bv[nf_][1], acc[2*(Q)+1][nf_], 0, 0, 0); \
    } \
    __builtin_amdgcn_s_setprio(0); }

  // PHASE: reads, stage, barrier, lgkm0(+fence, rule#18), MFMA, [VMC4], barrier
#define PHASE(DC, Q, RDBV, OPS, DS, HS, TKS, DOVMC) { \
    if (RDBV) READ_BV(DC); \
    READ_AF(DC, Q); \
    STAGEH(OPS, DS, HS, TKS); \
    FENCE; \
    __builtin_amdgcn_s_barrier(); \
    LGKM0; \
    FENCE; \
    MFMA16(Q); \
    FENCE; \
    if (DOVMC) { VMC4; FENCE; } \
    __builtin_amdgcn_s_barrier(); }

  // ---- prologue: A(0),B(0) -> dbuf0; B(1) -> dbuf1 (12 loads); wait 8 oldest ----
  STAGEH(0, 0, 0, 0);  STAGEH(0, 0, 1, 0);       // A(0) h0,h1
  STAGEH(1, 0, 0, 0);  STAGEH(1, 0, 1, 0);       // B(0) h0,h1
  STAGEH(1, 1, 0, 64); STAGEH(1, 1, 1, 64);      // B(1) h0,h1 (stay in flight)
  VMC4;
  FENCE;
  __builtin_amdgcn_s_barrier();

  for (int i = 0; i < 8; ++i) {
    const int t = 2 * i;
    const int kA1 = (t + 1) * 64;                          // A(t+1), real (t+1<=15)
    const int kB2 = ((t + 2 < NKT) ? t + 2 : NKT - 1) * 64; // clamped tail re-stage
    const int kA2 = kB2;
    const int kB3 = ((t + 3 < NKT) ? t + 3 : NKT - 1) * 64;
    // phases 1-4: compute tile t (dbuf0)
    PHASE(0, 0, 1, 0, 1, 0, kA1, 0);   // p1: +bv(t); stage Ah0(t+1)->d1
    PHASE(0, 1, 0, 0, 1, 1, kA1, 0);   // p2: stage Ah1(t+1)->d1
    PHASE(0, 2, 0, 1, 0, 0, kB2, 0);   // p3: stage Bh0(t+2)->d0
    PHASE(0, 3, 0, 1, 0, 1, kB2, 1);   // p4: stage Bh1(t+2)->d0; vmcnt(4)
    // phases 5-8: compute tile t+1 (dbuf1)
    PHASE(1, 0, 1, 0, 0, 0, kA2, 0);   // p5: +bv(t+1); stage Ah0(t+2)->d0
    PHASE(1, 1, 0, 0, 0, 1, kA2, 0);   // p6: stage Ah1(t+2)->d0
    PHASE(1, 2, 0, 1, 1, 0, kB3, 0);   // p7: stage Bh0(t+3)->d1
    PHASE(1, 3, 0, 1, 1, 1, kB3, 1);   // p8: stage Bh1(t+3)->d1; vmcnt(4)
  }
  asm volatile("s_waitcnt vmcnt(0)" ::: "memory");
  FENCE;
  __builtin_amdgcn_s_barrier();

  // ---- epilogue: tanh(acc + b1q) * V, reduce over u (r5-verified layout) ----
  const int b_blk = bm >> 3;                 // 256-row tile never crosses a batch
  float bqv[4], vvv[4];
#pragma unroll
  for (int nf = 0; nf < 4; ++nf) {
    const int ug = u0 + wn * 64 + nf * 16 + l15;   // D col = lane&15
    bqv[nf] = b1q[b_blk * U_ + ug];
    vvv[nf] = V[ug];
  }
  float rp[8][4];
#pragma unroll
  for (int mf = 0; mf < 8; ++mf)
#pragma unroll
    for (int j = 0; j < 4; ++j) rp[mf][j] = 0.f;
#pragma unroll
  for (int nf = 0; nf < 4; ++nf)
#pragma unroll
    for (int mf = 0; mf < 8; ++mf) {
      const f32x4 c = acc[mf][nf];
#pragma unroll
      for (int j = 0; j < 4; ++j) {
        const float x = c[j] + bqv[nf];
        const float e = __expf(2.f * x);     // inf-safe tanh
        const float tt = 1.f - 2.f / (e + 1.f);
        rp[mf][j] += tt * vvv[nf];
      }
    }
#pragma unroll
  for (int mf = 0; mf < 8; ++mf)
#pragma unroll
    for (int j = 0; j < 4; ++j) {
      float v = rp[mf][j];
      v += __shfl_xor(v, 1);
      v += __shfl_xor(v, 2);
      v += __shfl_xor(v, 4);
      v += __shfl_xor(v, 8);
      rp[mf][j] = v;
    }
  if (l15 == 0) {
#pragma unroll
    for (int mf = 0; mf < 8; ++mf)
#pragma unroll
      for (int j = 0; j < 4; ++j)
        scorebuf[(wm * 128 + mf * 16 + l16 * 4 + j) * 4 + wn] = rp[mf][j];
  }
  __syncthreads();
  if (tid < BMT) {
    const float s = scorebuf[tid * 4 + 0] + scorebuf[tid * 4 + 1] +
                    scorebuf[tid * 4 + 2] + scorebuf[tid * 4 + 3];
    score_part[(size_t)bn * (B_ * S_) + bm * BMT + tid] = s;
  }
}

// ---------- softmax over S per batch (4 u-partials; bV shift-invariant -> dropped) ----------
__global__ void k_softmax(const float* __restrict__ sp, float* __restrict__ aw) {
  __shared__ float red[8];
  const int b = blockIdx.x, tid = threadIdx.x;   // 256 threads, 8 elems each
  const int BS = B_ * S_;
  float x[8];
  float m = -1e30f;
#pragma unroll
  for (int i = 0; i < 8; ++i) {
    const int s = b * S_ + tid + i * 256;
    x[i] = sp[s] + sp[BS + s] + sp[2 * BS + s] + sp[3 * BS + s];
    m = fmaxf(m, x[i]);
  }
#pragma unroll
  for (int off = 32; off; off >>= 1) m = fmaxf(m, __shfl_xor(m, off));
  if ((tid & 63) == 0) red[tid >> 6] = m;
  __syncthreads();
  m = fmaxf(fmaxf(red[0], red[1]), fmaxf(red[2], red[3]));
  float e[8];
  float sum = 0.f;
#pragma unroll
  for (int i = 0; i < 8; ++i) { e[i] = __expf(x[i] - m); sum += e[i]; }
#pragma unroll
  for (int off = 32; off; off >>= 1) sum += __shfl_xor(sum, off);
  __syncthreads();
  if ((tid & 63) == 0) red[4 + (tid >> 6)] = sum;
  __syncthreads();
  sum = red[4] + red[5] + red[6] + red[7];
  const float inv = 1.f / sum;
#pragma unroll
  for (int i = 0; i < 8; ++i) aw[b * S_ + tid + i * 256] = e[i] * inv;
}

// ---------- context: partial weighted sums over s-chunks (bf16 values), then combine ----------
__global__ void k_ctx_partial(const unsigned short* __restrict__ vbf, const float* __restrict__ aw,
                              float* __restrict__ part) {
  __shared__ float a_s[128];
  const int b = blockIdx.y, sc = blockIdx.x, tid = threadIdx.x;  // 16 chunks x 128 s
  if (tid < 128) a_s[tid] = aw[b * S_ + sc * 128 + tid];
  __syncthreads();
  const unsigned short* vp = vbf + (size_t)(b * S_ + sc * 128) * H_ + tid * 4;
  float4 acc = {0.f, 0.f, 0.f, 0.f};
#pragma unroll 4
  for (int i = 0; i < 128; ++i) {
    const ushort4 v = *(const ushort4*)(vp + (size_t)i * H_);
    const float a = a_s[i];
    acc.x += a * bf2f(v.x); acc.y += a * bf2f(v.y);
    acc.z += a * bf2f(v.z); acc.w += a * bf2f(v.w);
  }
  ((float4*)part)[(size_t)(b * 16 + sc) * (H_ / 4) + tid] = acc;
}

__global__ void k_ctx_combine(const float* __restrict__ part, float* __restrict__ ctx) {
  const int b = blockIdx.x, tid = threadIdx.x;
  float4 s = {0.f, 0.f, 0.f, 0.f};
#pragma unroll
  for (int c = 0; c < 16; ++c) {
    const float4 v = ((const float4*)part)[(size_t)(b * 16 + c) * (H_ / 4) + tid];
    s.x += v.x; s.y += v.y; s.z += v.z; s.w += v.w;
  }
  ((float4*)ctx)[b * (H_ / 4) + tid] = s;
}

extern "C" void kernel_launch(void* const* d_in, const int* in_sizes, int n_in,
                              void* d_out, int out_size, void* d_ws, size_t ws_size,
                              hipStream_t stream) {
  const float* query  = (const float*)d_in[0];
  const float* values = (const float*)d_in[1];
  const float* W1     = (const float*)d_in[2];
  const float* b1     = (const float*)d_in[3];
  const float* W2     = (const float*)d_in[4];
  const float* b2     = (const float*)d_in[5];
  const float* V      = (const float*)d_in[6];
  // d_in[7] = bV: softmax shift-invariant, affects neither output -> unused.

  char* ws = (char*)d_ws;
  unsigned short* W1T = (unsigned short*)ws;                                   // 2 MB  [U][H] bf16
  float* b1q   = (float*)(ws + 2u * 1024u * 1024u);                            // 128 KB [B][U]
  float* spart = (float*)(ws + 2u * 1024u * 1024u + 128u * 1024u);             // 1 MB  [4][B*S]
  float* cpart = (float*)(ws + 3u * 1024u * 1024u + 128u * 1024u);             // 2 MB  [B*16][H]
  float* qpart = (float*)(ws + 5u * 1024u * 1024u + 128u * 1024u);             // 1 MB  [8][B][U]
  unsigned short* vbf = (unsigned short*)(ws + 8u * 1024u * 1024u);            // 128 MB [B*S][H] bf16

  float* aw  = (float*)d_out;        // [B,S,1]
  float* ctx = aw + B_ * S_;         // [B,H]

  k_transpose_w1<<<dim3(16, 16), dim3(64, 4), 0, stream>>>(W1, W1T);
  k_b1q_part<<<dim3(4, 8), dim3(256), 0, stream>>>(query, W2, qpart);
  k_b1q_comb<<<dim3(4, 32), dim3(256), 0, stream>>>(qpart, b1, b2, b1q);
  k_cvt<<<dim3(2048), dim3(256), 0, stream>>>(values, vbf);
  k_fused_score<<<dim3(1024), dim3(512), 0, stream>>>(vbf, W1T, b1q, V, spart);
  k_softmax<<<dim3(32), dim3(256), 0, stream>>>(spart, aw);
  k_ctx_partial<<<dim3(16, 32), dim3(256), 0, stream>>>(vbf, aw, cpart);
  k_ctx_combine<<<dim3(32), dim3(256), 0, stream>>>(cpart, ctx);
}